// Round 9
// baseline (869.052 us; speedup 1.0000x reference)
//
#include <hip/hip_runtime.h>
#include <hip/hip_bf16.h>
#include <math.h>

typedef unsigned short u16;
typedef unsigned int u32;
typedef _Float16 f16;
typedef _Float16 f16x8 __attribute__((ext_vector_type(8)));
typedef float f32x4 __attribute__((ext_vector_type(4)));

// ---------------- constants ----------------
#define BATCH 32
#define CIN   1024
#define COUT  512
#define NPOS  8192
#define K9    9216
#define KHALF 4608
#define TOPK  30
#define NROI  960
#define POOLN 7
#define IMG   256

// ---------------- ws layout (float units) ----------------
#define O_XP0  0ull
#define O_XP1  4194304ull
#define O_CH   8388608ull      // u16[8388608]
#define O_CL   12582912ull
#define O_WH   16777216ull     // u16[4718592]
#define O_WL   19136512ull
#define O_Z    21495808ull     // 512 u16 zeros
#define O_HW   21496064ull
#define O_SC   21519104ull
#define O_RG   21592832ull
#define O_ROI  21887744ull
#define O_VAL  21891584ull
#define O_LAB  21892544ull
#define O_W1T  21893504ull     // float[262144] w1 transposed [c][o]
#define O_W2T  22155648ull     // float[65536]  w2 transposed [c][o]
#define WS_FLOATS 22221184ull
// overlays on XP0/XP1 region (used only after heads consumed XP0/XP1):
#define O_PO   0ull
#define O_NF   1474560ull
#define O_RL   1720320ull
#define O_RA   1721280ull

// async global->LDS, 16 bytes/lane, LDS dest = wave-uniform base + lane*16
__device__ __forceinline__ void gl_lds16(const void* g, void* l) {
    __builtin_amdgcn_global_load_lds(
        (const __attribute__((address_space(1))) u32*)g,
        (__attribute__((address_space(3))) u32*)l,
        16, 0, 0);
}

// ---------------- fp16 hi/lo split ----------------
__device__ inline void split16(float x, u16& h, u16& l) {
    f16 hv = (f16)x;
    f16 lv = (f16)(x - (float)hv);
    h = *(u16*)&hv;
    l = *(u16*)&lv;
}

// ---------------- fused prep ----------------
#define NB_CLIP 8192
#define NB_W    2048
#define NB_Z    1
#define NB_HW   90
#define NB_W1T  1024
#define NB_W2T  256
__global__ __launch_bounds__(256)
void convert_all(const float* __restrict__ clip, const float* __restrict__ conv_w,
                 const float* __restrict__ cls_w, const float* __restrict__ reg_w,
                 const float* __restrict__ w1, const float* __restrict__ w2,
                 u16* __restrict__ CH, u16* __restrict__ CL,
                 u16* __restrict__ WH, u16* __restrict__ WL,
                 u16* __restrict__ Z, float* __restrict__ HW,
                 float* __restrict__ w1T, float* __restrict__ w2T) {
    __shared__ float wsh[2304];
    int bid = blockIdx.x, t = threadIdx.x;
    if (bid < NB_CLIP) {
        int tid = bid * 256 + t;
        int c4  = (tid & 255) * 4;
        int pos = (tid >> 8) & 255;
        int b   = tid >> 16;
        float4 v = *(const float4*)(clip + ((size_t)(1 + pos) * 32 + b) * 1024 + c4);
        float xs[4] = {v.x, v.y, v.z, v.w};
        ushort4 hh, ll;
        u16* hp = (u16*)&hh; u16* lp = (u16*)&ll;
#pragma unroll
        for (int q = 0; q < 4; ++q) split16(xs[q], hp[q], lp[q]);
        size_t o = ((size_t)(b * 256 + pos)) * 1024 + c4;
        *(ushort4*)(CH + o) = hh;
        *(ushort4*)(CL + o) = ll;
    } else if (bid < NB_CLIP + NB_W) {
        // coalesced conv_w convert: block = (o, cblk of 256 c's)
        int bid2 = bid - NB_CLIP;
        int o = bid2 >> 2, cblk = bid2 & 3;
        const float* src = conv_w + (size_t)o * K9 + cblk * 2304;
        for (int i = t; i < 2304; i += 256) wsh[i] = src[i];   // fully coalesced
        __syncthreads();
#pragma unroll
        for (int p = 0; p < 9; ++p) {
            float x = wsh[t * 9 + p];
            u16 h, l;
            split16(x, h, l);
            size_t o2 = (size_t)o * K9 + p * 1024 + cblk * 256 + t;  // coalesced
            WH[o2] = h; WL[o2] = l;
        }
    } else if (bid < NB_CLIP + NB_W + NB_Z) {
        Z[t] = 0; Z[256 + t] = 0;
    } else if (bid < NB_CLIP + NB_W + NB_Z + NB_HW) {
        int tid2 = (bid - NB_CLIP - NB_W - NB_Z) * 256 + t;
        if (tid2 < 45 * 512) {
            int c = tid2 / 45, a = tid2 % 45;
            HW[tid2] = (a < 9) ? cls_w[a * 512 + c] : reg_w[(a - 9) * 512 + c];
        }
    } else if (bid < NB_CLIP + NB_W + NB_Z + NB_HW + NB_W1T) {
        int tid2 = (bid - NB_CLIP - NB_W - NB_Z - NB_HW) * 256 + t;   // 262144
        int o = tid2 >> 10, c = tid2 & 1023;
        w1T[c * 256 + o] = w1[(size_t)o * 1024 + c];
    } else {
        int tid2 = (bid - NB_CLIP - NB_W - NB_Z - NB_HW - NB_W1T) * 256 + t; // 65536
        int o = tid2 >> 8, c = tid2 & 255;
        w2T[c * 256 + o] = w2[(size_t)o * 256 + c];
    }
}

// ---------------- MFMA conv GEMM (fp16x2 split, 3 MFMA/product) ----------------
// Round-8 version unchanged: TM=TN=128, BK=32, grid 512, dbuf LDS, one barrier
// per iteration, round-6 XCD decode. Per-output accumulation order bit-identical.
__global__ __launch_bounds__(256, 2)
void conv_mfma(const u16* __restrict__ CH, const u16* __restrict__ CL,
               const u16* __restrict__ WH, const u16* __restrict__ WL,
               const u16* __restrict__ ZS,
               float* __restrict__ XP0, float* __restrict__ XP1) {
    __shared__ __align__(16) u16 Ah[8192];   // 2 buffers x (128 rows x 32 k)
    __shared__ __align__(16) u16 Al[8192];
    __shared__ __align__(16) u16 Bh[8192];
    __shared__ __align__(16) u16 Bl[8192];

    const int t = threadIdx.x;
    const int gid = blockIdx.x;
    const int nb = gid >> 7;            // 0..3
    const int g  = gid & 127;
    const int mb = g >> 1;              // 0..63
    const int ks = g & 1;
    const int ksOff = ks * KHALF;
    float* __restrict__ XP = ks ? XP1 : XP0;

    const int wave = t >> 6, lane = t & 63;

    int qA[2], siA[2], sjA[2], bA[2];
    const u16* srcBh[2];
    const u16* srcBl[2];
#pragma unroll
    for (int j = 0; j < 2; ++j) {
        int r = wave * 32 + j * 16 + (lane >> 2);
        int s = lane & 3;
        int q = s ^ ((r >> 1) & 3);
        qA[j] = q;
        int m = mb * 128 + r;
        bA[j] = m >> 8;
        int ij = m & 255;
        siA[j] = ij >> 4; sjA[j] = ij & 15;
        int o = nb * 128 + r;
        srcBh[j] = WH + (size_t)o * K9 + q * 8;
        srcBl[j] = WL + (size_t)o * K9 + q * 8;
    }

    const int wm = wave >> 1, wn = wave & 1;
    const int l16 = lane & 15, quad = lane >> 4;
    int offA[4], offB[4];
#pragma unroll
    for (int q = 0; q < 4; ++q) {
        int ar = wm * 64 + q * 16 + l16;
        offA[q] = ar * 32 + ((quad ^ ((ar >> 1) & 3)) << 3);
        int br = wn * 64 + q * 16 + l16;
        offB[q] = br * 32 + ((quad ^ ((br >> 1) & 3)) << 3);
    }

    f32x4 acc[4][4];
#pragma unroll
    for (int r = 0; r < 4; ++r)
#pragma unroll
        for (int c = 0; c < 4; ++c) acc[r][c] = (f32x4){0.f, 0.f, 0.f, 0.f};

    auto issue = [&](int it, int buf) {
        const int kg = ksOff + it * 32;
        const int p = kg >> 10;
        const int cb = kg & 1023;
        const int di = p / 3, dj = p - di * 3;
        const int base = buf << 12;
#pragma unroll
        for (int j = 0; j < 2; ++j) {
            int ii = siA[j] + di - 1, jj = sjA[j] + dj - 1;
            bool ok = ((unsigned)ii < 16u) && ((unsigned)jj < 16u);
            size_t aoff = ok ? ((((size_t)bA[j] << 8) + (size_t)(ii * 16 + jj)) << 10) + cb + qA[j] * 8
                             : 0;
            const u16* gah = ok ? CH + aoff : ZS;
            const u16* gal = ok ? CL + aoff : ZS;
            int lb = base + wave * 1024 + j * 512;
            gl_lds16(gah,           &Ah[lb]);
            gl_lds16(gal,           &Al[lb]);
            gl_lds16(srcBh[j] + kg, &Bh[lb]);
            gl_lds16(srcBl[j] + kg, &Bl[lb]);
        }
    };

    issue(0, 0);
    for (int it = 0; it < 144; ++it) {
        const int cur = it & 1;
        __syncthreads();
        if (it + 1 < 144) issue(it + 1, cur ^ 1);

        const int fb = cur << 12;
        f16x8 fah[4], fal[4], fbh[4], fbl[4];
#pragma unroll
        for (int x = 0; x < 4; ++x) {
            fah[x] = *(const f16x8*)&Ah[fb + offA[x]];
            fal[x] = *(const f16x8*)&Al[fb + offA[x]];
            fbh[x] = *(const f16x8*)&Bh[fb + offB[x]];
            fbl[x] = *(const f16x8*)&Bl[fb + offB[x]];
        }
#pragma unroll
        for (int tm = 0; tm < 4; ++tm)
#pragma unroll
            for (int tn = 0; tn < 4; ++tn) {
                acc[tm][tn] = __builtin_amdgcn_mfma_f32_16x16x32_f16(fal[tm], fbh[tn], acc[tm][tn], 0, 0, 0);
                acc[tm][tn] = __builtin_amdgcn_mfma_f32_16x16x32_f16(fah[tm], fbl[tn], acc[tm][tn], 0, 0, 0);
                acc[tm][tn] = __builtin_amdgcn_mfma_f32_16x16x32_f16(fah[tm], fbh[tn], acc[tm][tn], 0, 0, 0);
            }
    }

#pragma unroll
    for (int tm = 0; tm < 4; ++tm) {
        int mbase = mb * 128 + wm * 64 + tm * 16 + quad * 4;
#pragma unroll
        for (int tn = 0; tn < 4; ++tn) {
            int o = nb * 128 + wn * 64 + tn * 16 + l16;
#pragma unroll
            for (int r = 0; r < 4; ++r)
                XP[(size_t)(mbase + r) * COUT + o] = acc[tm][tn][r];
        }
    }
}

// ---------------- heads (unchanged math) ----------------
__global__ __launch_bounds__(64)
void heads_kernel(const float* __restrict__ XP0, const float* __restrict__ XP1,
                  const float* __restrict__ conv_b, const float* __restrict__ HW,
                  const float* __restrict__ cls_b, const float* __restrict__ reg_b,
                  float* __restrict__ scores, float* __restrict__ regs) {
    __shared__ float xs[512];
    int mm = blockIdx.x;
    int t = threadIdx.x;
#pragma unroll
    for (int q = 0; q < 8; ++q) {
        int c = t + 64 * q;
        xs[c] = fmaxf(XP0[(size_t)mm * COUT + c] + XP1[(size_t)mm * COUT + c] + conv_b[c], 0.f);
    }
    __syncthreads();
    if (t < 45) {
        float acc = (t < 9) ? cls_b[t] : reg_b[t - 9];
        for (int c = 0; c < 512; ++c) acc = fmaf(xs[c], HW[c * 45 + t], acc);
        int b = mm >> 8, cell = mm & 255;
        if (t < 9) {
            scores[(size_t)b * 2304 + cell * 9 + t] = 1.f / (1.f + expf(-acc));
        } else {
            int ch = t - 9;
            regs[((size_t)b * 2304 + cell * 9 + (ch >> 2)) * 4 + (ch & 3)] = acc;
        }
    }
}

// ---------------- top-k + decode + NMS per image (unchanged) ----------------
__global__ __launch_bounds__(256)
void topk_nms(const float* __restrict__ scores, const float* __restrict__ regs,
              float* __restrict__ rois, float* __restrict__ valid) {
    __shared__ float sc[2304];
    __shared__ float wv[4];
    __shared__ int   wi[4];
    __shared__ int   sel[TOPK];
    __shared__ float bx[TOPK][4];
    __shared__ float iou[TOPK * TOPK];
    __shared__ float keepsh[TOPK];
    int b = blockIdx.x, t = threadIdx.x;
    for (int q = t; q < 2304; q += 256) sc[q] = scores[(size_t)b * 2304 + q];
    __syncthreads();

    for (int k = 0; k < TOPK; ++k) {
        float bv = -1e30f; int bi = 1 << 30;
#pragma unroll
        for (int q = 0; q < 9; ++q) {
            int idx = t * 9 + q;
            float v = sc[idx];
            if (v > bv || (v == bv && idx < bi)) { bv = v; bi = idx; }
        }
        for (int off = 32; off; off >>= 1) {
            float ov = __shfl_down(bv, off);
            int   oi = __shfl_down(bi, off);
            if (ov > bv || (ov == bv && oi < bi)) { bv = ov; bi = oi; }
        }
        int lane = t & 63, w = t >> 6;
        if (lane == 0) { wv[w] = bv; wi[w] = bi; }
        __syncthreads();
        if (t == 0) {
            float fv = wv[0]; int fi = wi[0];
            for (int q = 1; q < 4; ++q)
                if (wv[q] > fv || (wv[q] == fv && wi[q] < fi)) { fv = wv[q]; fi = wi[q]; }
            sel[k] = fi;
            sc[fi] = -1e38f;
        }
        __syncthreads();
    }

    if (t < TOPK) {
        int n = sel[t];
        int cell = n / 9, a = n % 9;
        int ci = cell >> 4, cj = cell & 15;
        int siid = a / 3, riid = a % 3;
        const double scl[3] = {8.0, 16.0, 32.0};
        const double rat[3] = {0.5, 1.0, 2.0};
        double s = scl[siid], r = rat[riid];
        double wD = s * sqrt(r), hD = s / sqrt(r);
        double xc = (cj + 0.5) * 16.0, yc = (ci + 0.5) * 16.0;
        float ax1 = (float)(xc - wD / 2), ay1 = (float)(yc - hD / 2);
        float ax2 = (float)(xc + wD / 2), ay2 = (float)(yc + hD / 2);
        float aw = ax2 - ax1, ah = ay2 - ay1;
        float ctrx = ax1 + 0.5f * aw, ctry = ay1 + 0.5f * ah;
        const float* rg = regs + ((size_t)b * 2304 + n) * 4;
        float cx = rg[0] * aw + ctrx;
        float cy = rg[1] * ah + ctry;
        float pw = expf(rg[2]) * aw;
        float ph = expf(rg[3]) * ah;
        float x1 = cx - 0.5f * pw, y1 = cy - 0.5f * ph;
        float x2 = cx + 0.5f * pw, y2 = cy + 0.5f * ph;
        x1 = fminf(fmaxf(x1, 0.f), 256.f);
        y1 = fminf(fmaxf(y1, 0.f), 256.f);
        x2 = fminf(fmaxf(x2, 0.f), 256.f);
        y2 = fminf(fmaxf(y2, 0.f), 256.f);
        if (x2 - x1 < 1.f) x2 = x1 + 1.f;
        if (y2 - y1 < 1.f) y2 = y1 + 1.f;
        bx[t][0] = x1; bx[t][1] = y1; bx[t][2] = x2; bx[t][3] = y2;
    }
    __syncthreads();
    if (t < TOPK * TOPK) {
        int ii = t / TOPK, jj = t % TOPK;
        float xi1 = bx[ii][0], yi1 = bx[ii][1], xi2 = bx[ii][2], yi2 = bx[ii][3];
        float xj1 = bx[jj][0], yj1 = bx[jj][1], xj2 = bx[jj][2], yj2 = bx[jj][3];
        float ai = (xi2 - xi1) * (yi2 - yi1), aj = (xj2 - xj1) * (yj2 - yj1);
        float iw = fmaxf(fminf(xi2, xj2) - fmaxf(xi1, xj1), 0.f);
        float ih = fmaxf(fminf(yi2, yj2) - fmaxf(yi1, yj1), 0.f);
        float inter = iw * ih;
        iou[t] = inter / (ai + aj - inter);
    }
    __syncthreads();
    if (t == 0) {
        bool keep[TOPK];
        for (int q = 0; q < TOPK; ++q) keep[q] = true;
        for (int iK = 0; iK < TOPK; ++iK) {
            if (!keep[iK]) continue;
            for (int jK = iK + 1; jK < TOPK; ++jK)
                if (keep[jK] && iou[iK * TOPK + jK] > 0.85f) keep[jK] = false;
        }
        for (int q = 0; q < TOPK; ++q) keepsh[q] = keep[q] ? 1.f : 0.f;
    }
    __syncthreads();
    if (t < TOPK) {
        int rr = b * TOPK + t;
        rois[rr * 4 + 0] = bx[t][0]; rois[rr * 4 + 1] = bx[t][1];
        rois[rr * 4 + 2] = bx[t][2]; rois[rr * 4 + 3] = bx[t][3];
        valid[rr] = keepsh[t];
    }
}

// ---------------- roi-align, image-sliced: one block per (image, 64-ch group) ----
// Stages the 256x64 fp32 clip slice into LDS once (clip read exactly once
// globally). Wave w handles roi 4*rp+w (wave-uniform control flow). Per-channel
// sample loop order identical to the reference -> same fp32 result class.
__global__ __launch_bounds__(256)
void align_img(const float* __restrict__ clip, const float* __restrict__ rois,
               float* __restrict__ pooled) {
    __shared__ float slice[16384];   // 64 KB: [pos 0..255][ch 0..63]
    int bid = blockIdx.x;            // 0..511
    int b = bid >> 4, cg = bid & 15;
    int t = threadIdx.x;
    for (int idx = t; idx < 16384; idx += 256) {
        int p = idx >> 6, c = idx & 63;
        slice[idx] = clip[(size_t)(1 + p) * 32768 + (size_t)b * 1024 + cg * 64 + c];
    }
    __syncthreads();
    int wv = t >> 6;            // wave = roi sub-index
    int ch = t & 63;
    for (int rp = 0; rp < 8; ++rp) {
        int rl = rp * 4 + wv;               // 0..31; skip >=30 (wave-uniform)
        if (rl >= TOPK) continue;
        int r = b * TOPK + rl;
        float rx1 = rois[r * 4 + 0] * 0.0625f, ry1 = rois[r * 4 + 1] * 0.0625f;
        float rw = fmaxf(rois[r * 4 + 2] * 0.0625f - rx1, 1.f);
        float rh = fmaxf(rois[r * 4 + 3] * 0.0625f - ry1, 1.f);
        float sx = rw / (float)POOLN, sy = rh / (float)POOLN;
        float acc = 0.f;
        for (int py = 0; py < POOLN; ++py) {
            float Y = ry1 + ((float)py + 0.5f) * sy;
            for (int px = 0; px < POOLN; ++px) {
                float Xx = rx1 + ((float)px + 0.5f) * sx;
                bool ok = (Y > -1.f) && (Y < 16.f) && (Xx > -1.f) && (Xx < 16.f);
                if (!ok) continue;
                float Xc = fminf(fmaxf(Xx, 0.f), 15.f);
                float Yc = fminf(fmaxf(Y, 0.f), 15.f);
                int x0 = (int)floorf(Xc), y0 = (int)floorf(Yc);
                int x1i = min(x0 + 1, 15), y1i = min(y0 + 1, 15);
                float lx = Xc - (float)x0, ly = Yc - (float)y0;
                float hx = 1.f - lx, hy = 1.f - ly;
                float w00 = hy * hx, w01 = hy * lx, w10 = ly * hx, w11 = ly * lx;
                float f00 = slice[(y0 * 16 + x0) * 64 + ch];
                float f01 = slice[(y0 * 16 + x1i) * 64 + ch];
                float f10 = slice[(y1i * 16 + x0) * 64 + ch];
                float f11 = slice[(y1i * 16 + x1i) * 64 + ch];
                acc += w00 * f00 + w01 * f01 + w10 * f10 + w11 * f11;
            }
        }
        pooled[(size_t)r * 1024 + cg * 64 + ch] = acc / 49.f;
    }
}

// ---------------- roi labels (no-div row walk, unchanged math) ----------------
__global__ __launch_bounds__(256)
void labels_k(const float* __restrict__ gt, const float* __restrict__ rois,
              float* __restrict__ labels) {
    __shared__ float red[4];
    int r = blockIdx.x, t = threadIdx.x;
    int b = r / TOPK;
    int x1 = min(max((int)rois[r * 4 + 0], 0), 256);
    int y1 = min(max((int)rois[r * 4 + 1], 0), 256);
    int x2 = min(max((int)rois[r * 4 + 2], 0), 256);
    int y2 = min(max((int)rois[r * 4 + 3], 0), 256);
    int cnt = (x2 - x1) * (y2 - y1);
    float s = 0.f;
    if (cnt > 0) {
        const float* g = gt + (size_t)b * (IMG * IMG);
        for (int yy = y1; yy < y2; ++yy) {
            const float* row = g + yy * IMG;
            for (int xx = x1 + t; xx < x2; xx += 256) s += row[xx];
        }
    }
    for (int off = 32; off; off >>= 1) s += __shfl_down(s, off);
    if ((t & 63) == 0) red[t >> 6] = s;
    __syncthreads();
    if (t == 0) {
        float tot = red[0] + red[1] + red[2] + red[3];
        labels[r] = (cnt > 0 && 2.f * tot > (float)cnt) ? 1.f : 0.f;
    }
}

// ---------------- fused fc1(relu) -> fc2 -> normalize, 4 rois/block ----------------
__global__ __launch_bounds__(256)
void fc_norm(const float* __restrict__ pooled, const float* __restrict__ w1T,
             const float* __restrict__ b1, const float* __restrict__ w2T,
             const float* __restrict__ b2, float* __restrict__ nf) {
    __shared__ float rows[4][1024];
    __shared__ float hsh[4][256];
    __shared__ float red[4];
    int r0 = blockIdx.x * 4, t = threadIdx.x;
    for (int q = 0; q < 4; ++q)
        for (int c = t; c < 1024; c += 256)
            rows[q][c] = pooled[(size_t)(r0 + q) * 1024 + c];
    __syncthreads();
    {
        float bv = b1[t];
        float acc[4] = {bv, bv, bv, bv};
        for (int c = 0; c < 1024; ++c) {
            float wv = w1T[c * 256 + t];
#pragma unroll
            for (int q = 0; q < 4; ++q) acc[q] = fmaf(rows[q][c], wv, acc[q]);
        }
#pragma unroll
        for (int q = 0; q < 4; ++q) hsh[q][t] = fmaxf(acc[q], 0.f);
    }
    __syncthreads();
    float pr[4];
    {
        float bv = b2[t];
        float acc[4] = {bv, bv, bv, bv};
        for (int c = 0; c < 256; ++c) {
            float wv = w2T[c * 256 + t];
#pragma unroll
            for (int q = 0; q < 4; ++q) acc[q] = fmaf(hsh[q][c], wv, acc[q]);
        }
#pragma unroll
        for (int q = 0; q < 4; ++q) pr[q] = acc[q];
    }
    for (int q = 0; q < 4; ++q) {
        float v = pr[q];
        float ss = v * v;
        for (int off = 32; off; off >>= 1) ss += __shfl_down(ss, off);
        if ((t & 63) == 0) red[t >> 6] = ss;
        __syncthreads();
        float tot = red[0] + red[1] + red[2] + red[3];
        float denom = fmaxf(sqrtf(tot), 1e-12f);
        nf[(size_t)(r0 + q) * 256 + t] = v / denom;
        __syncthreads();
    }
}

// ---------------- supcon, 4 i-rows per block (round-5-verified, nf traffic /4) ----
__global__ __launch_bounds__(256)
void supcon_rows4(const float* __restrict__ nf, const float* __restrict__ labels,
                  const float* __restrict__ valid, float* __restrict__ rowl,
                  float* __restrict__ rowa) {
    __shared__ float my[4][256];
    __shared__ float labs[NROI], vals[NROI];
    __shared__ float wsa[4][4], wsp[4][4];
    __shared__ int wnp[4][4];
    int i0 = blockIdx.x * 4, t = threadIdx.x;
#pragma unroll
    for (int iq = 0; iq < 4; ++iq) my[iq][t] = nf[(size_t)(i0 + iq) * 256 + t];
    for (int q = t; q < NROI; q += 256) { labs[q] = labels[q]; vals[q] = valid[q]; }
    __syncthreads();
    int w = t >> 6, lane = t & 63;
    float4 my4[4];
    float vi[4], li[4];
#pragma unroll
    for (int iq = 0; iq < 4; ++iq) {
        my4[iq] = ((const float4*)my[iq])[lane];
        vi[iq] = vals[i0 + iq];
        li[iq] = labs[i0 + iq];
    }
    float sa[4] = {0.f, 0.f, 0.f, 0.f}, sp[4] = {0.f, 0.f, 0.f, 0.f};
    int np[4] = {0, 0, 0, 0};
    for (int j = w; j < NROI; j += 4) {
        float4 v4 = ((const float4*)(nf + (size_t)j * 256))[lane];
        float vj = vals[j], lj = labs[j];
#pragma unroll
        for (int iq = 0; iq < 4; ++iq) {
            float p = my4[iq].x * v4.x;
            p = fmaf(my4[iq].y, v4.y, p);
            p = fmaf(my4[iq].z, v4.z, p);
            p = fmaf(my4[iq].w, v4.w, p);
#pragma unroll
            for (int off = 32; off; off >>= 1) p += __shfl_xor(p, off);
            if (vi[iq] > 0.5f && j != i0 + iq && vj > 0.5f) {
                float e = expf(p / 0.07f);
                sa[iq] += e;
                if (lj == li[iq]) { sp[iq] += e; np[iq]++; }
            }
        }
    }
    if (lane == 0) {
#pragma unroll
        for (int iq = 0; iq < 4; ++iq) { wsa[iq][w] = sa[iq]; wsp[iq][w] = sp[iq]; wnp[iq][w] = np[iq]; }
    }
    __syncthreads();
    if (t == 0) {
#pragma unroll
        for (int iq = 0; iq < 4; ++iq) {
            float s_a = wsa[iq][0] + wsa[iq][1] + wsa[iq][2] + wsa[iq][3];
            float s_p = wsp[iq][0] + wsp[iq][1] + wsp[iq][2] + wsp[iq][3];
            int tnp = wnp[iq][0] + wnp[iq][1] + wnp[iq][2] + wnp[iq][3];
            bool active = (vi[iq] > 0.5f) && (tnp > 0);
            float ratio = s_p / (s_a + 1e-12f);
            float l = -logf(ratio + 1e-12f);
            rowl[i0 + iq] = active ? l : 0.f;
            rowa[i0 + iq] = active ? 1.f : 0.f;
        }
    }
}

// ---------------- final scalar reduce (unchanged) ----------------
__global__ __launch_bounds__(256)
void final_reduce(const float* __restrict__ rowl, const float* __restrict__ rowa,
                  float* __restrict__ out) {
    __shared__ float rl[4], ra[4];
    int t = threadIdx.x;
    float sl = 0.f, sa = 0.f;
    for (int q = t; q < NROI; q += 256) { sl += rowl[q]; sa += rowa[q]; }
    for (int off = 32; off; off >>= 1) { sl += __shfl_down(sl, off); sa += __shfl_down(sa, off); }
    if ((t & 63) == 0) { rl[t >> 6] = sl; ra[t >> 6] = sa; }
    __syncthreads();
    if (t == 0) {
        float L = rl[0] + rl[1] + rl[2] + rl[3];
        float A = ra[0] + ra[1] + ra[2] + ra[3];
        out[0] = (A > 0.f) ? (L / fmaxf(A, 1.f)) : 0.f;
    }
}

// ---------------- launch ----------------
extern "C" void kernel_launch(void* const* d_in, const int* in_sizes, int n_in,
                              void* d_out, int out_size, void* d_ws, size_t ws_size,
                              hipStream_t stream) {
    const float* clip   = (const float*)d_in[0];
    const float* gt     = (const float*)d_in[1];
    const float* conv_w = (const float*)d_in[2];
    const float* conv_b = (const float*)d_in[3];
    const float* cls_w  = (const float*)d_in[4];
    const float* cls_b  = (const float*)d_in[5];
    const float* reg_w  = (const float*)d_in[6];
    const float* reg_b  = (const float*)d_in[7];
    const float* w1     = (const float*)d_in[8];
    const float* b1     = (const float*)d_in[9];
    const float* w2     = (const float*)d_in[10];
    const float* b2     = (const float*)d_in[11];

    if (ws_size < WS_FLOATS * sizeof(float)) return;  // visible failure if ws too small

    float* ws  = (float*)d_ws;
    float* XP0 = ws + O_XP0;
    float* XP1 = ws + O_XP1;
    u16*   CH  = (u16*)(ws + O_CH);
    u16*   CL  = (u16*)(ws + O_CL);
    u16*   WHp = (u16*)(ws + O_WH);
    u16*   WLp = (u16*)(ws + O_WL);
    u16*   ZS  = (u16*)(ws + O_Z);
    float* HW  = ws + O_HW;
    float* SC  = ws + O_SC;
    float* RG  = ws + O_RG;
    float* ROI = ws + O_ROI;
    float* VAL = ws + O_VAL;
    float* LAB = ws + O_LAB;
    float* W1T = ws + O_W1T;
    float* W2T = ws + O_W2T;
    float* PO  = ws + O_PO;
    float* NF  = ws + O_NF;
    float* RL  = ws + O_RL;
    float* RA  = ws + O_RA;

    convert_all<<<NB_CLIP + NB_W + NB_Z + NB_HW + NB_W1T + NB_W2T, 256, 0, stream>>>(
        clip, conv_w, cls_w, reg_w, w1, w2, CH, CL, WHp, WLp, ZS, HW, W1T, W2T);
    conv_mfma<<<512, 256, 0, stream>>>(CH, CL, WHp, WLp, ZS, XP0, XP1);
    heads_kernel<<<NPOS, 64, 0, stream>>>(XP0, XP1, conv_b, HW, cls_b, reg_b, SC, RG);
    topk_nms<<<BATCH, 256, 0, stream>>>(SC, RG, ROI, VAL);
    align_img<<<512, 256, 0, stream>>>(clip, ROI, PO);
    labels_k<<<NROI, 256, 0, stream>>>(gt, ROI, LAB);
    fc_norm<<<NROI / 4, 256, 0, stream>>>(PO, W1T, b1, W2T, b2, NF);
    supcon_rows4<<<NROI / 4, 256, 0, stream>>>(NF, LAB, VAL, RL, RA);
    final_reduce<<<1, 256, 0, stream>>>(RL, RA, (float*)d_out);
}

// Round 10
// 681.920 us; speedup vs baseline: 1.2744x; 1.2744x over previous
//
#include <hip/hip_runtime.h>
#include <hip/hip_bf16.h>
#include <math.h>

typedef unsigned short u16;
typedef unsigned int u32;
typedef _Float16 f16;
typedef _Float16 f16x8 __attribute__((ext_vector_type(8)));
typedef float f32x4 __attribute__((ext_vector_type(4)));

// ---------------- constants ----------------
#define BATCH 32
#define CIN   1024
#define COUT  512
#define NPOS  8192
#define K9    9216
#define KHALF 4608
#define TOPK  30
#define NROI  960
#define POOLN 7
#define IMG   256

// ---------------- ws layout (float units) ----------------
#define O_XP0  0ull
#define O_XP1  4194304ull
#define O_CH   8388608ull      // u16[8388608]
#define O_CL   12582912ull
#define O_WH   16777216ull     // u16[4718592]
#define O_WL   19136512ull
#define O_Z    21495808ull     // 512 u16 zeros
#define O_HW   21496064ull
#define O_SC   21519104ull
#define O_RG   21592832ull
#define O_ROI  21887744ull
#define O_VAL  21891584ull
#define O_LAB  21892544ull
#define O_W1T  21893504ull     // float[262144] w1 transposed [c][o]
#define O_W2T  22155648ull     // float[65536]  w2 transposed [c][o]
#define WS_FLOATS 22221184ull
// overlays on XP0/XP1 region (used only after heads consumed XP0/XP1):
#define O_PO   0ull
#define O_NF   1474560ull
#define O_PS   1720320ull      // float[960][2][3] supcon partials

// async global->LDS, 16 bytes/lane, LDS dest = wave-uniform base + lane*16
__device__ __forceinline__ void gl_lds16(const void* g, void* l) {
    __builtin_amdgcn_global_load_lds(
        (const __attribute__((address_space(1))) u32*)g,
        (__attribute__((address_space(3))) u32*)l,
        16, 0, 0);
}

// ---------------- fp16 hi/lo split ----------------
__device__ inline void split16(float x, u16& h, u16& l) {
    f16 hv = (f16)x;
    f16 lv = (f16)(x - (float)hv);
    h = *(u16*)&hv;
    l = *(u16*)&lv;
}

// ---------------- fused prep ----------------
#define NB_CLIP 8192
#define NB_W    2048
#define NB_Z    1
#define NB_HW   90
#define NB_W1T  1024
#define NB_W2T  256
__global__ __launch_bounds__(256)
void convert_all(const float* __restrict__ clip, const float* __restrict__ conv_w,
                 const float* __restrict__ cls_w, const float* __restrict__ reg_w,
                 const float* __restrict__ w1, const float* __restrict__ w2,
                 u16* __restrict__ CH, u16* __restrict__ CL,
                 u16* __restrict__ WH, u16* __restrict__ WL,
                 u16* __restrict__ Z, float* __restrict__ HW,
                 float* __restrict__ w1T, float* __restrict__ w2T) {
    __shared__ float wsh[2304];
    int bid = blockIdx.x, t = threadIdx.x;
    if (bid < NB_CLIP) {
        int tid = bid * 256 + t;
        int c4  = (tid & 255) * 4;
        int pos = (tid >> 8) & 255;
        int b   = tid >> 16;
        float4 v = *(const float4*)(clip + ((size_t)(1 + pos) * 32 + b) * 1024 + c4);
        float xs[4] = {v.x, v.y, v.z, v.w};
        ushort4 hh, ll;
        u16* hp = (u16*)&hh; u16* lp = (u16*)&ll;
#pragma unroll
        for (int q = 0; q < 4; ++q) split16(xs[q], hp[q], lp[q]);
        size_t o = ((size_t)(b * 256 + pos)) * 1024 + c4;
        *(ushort4*)(CH + o) = hh;
        *(ushort4*)(CL + o) = ll;
    } else if (bid < NB_CLIP + NB_W) {
        int bid2 = bid - NB_CLIP;
        int o = bid2 >> 2, cblk = bid2 & 3;
        const float* src = conv_w + (size_t)o * K9 + cblk * 2304;
        for (int i = t; i < 2304; i += 256) wsh[i] = src[i];
        __syncthreads();
#pragma unroll
        for (int p = 0; p < 9; ++p) {
            float x = wsh[t * 9 + p];
            u16 h, l;
            split16(x, h, l);
            size_t o2 = (size_t)o * K9 + p * 1024 + cblk * 256 + t;
            WH[o2] = h; WL[o2] = l;
        }
    } else if (bid < NB_CLIP + NB_W + NB_Z) {
        Z[t] = 0; Z[256 + t] = 0;
    } else if (bid < NB_CLIP + NB_W + NB_Z + NB_HW) {
        int tid2 = (bid - NB_CLIP - NB_W - NB_Z) * 256 + t;
        if (tid2 < 45 * 512) {
            int c = tid2 / 45, a = tid2 % 45;
            HW[tid2] = (a < 9) ? cls_w[a * 512 + c] : reg_w[(a - 9) * 512 + c];
        }
    } else if (bid < NB_CLIP + NB_W + NB_Z + NB_HW + NB_W1T) {
        int tid2 = (bid - NB_CLIP - NB_W - NB_Z - NB_HW) * 256 + t;
        int o = tid2 >> 10, c = tid2 & 1023;
        w1T[c * 256 + o] = w1[(size_t)o * 1024 + c];
    } else {
        int tid2 = (bid - NB_CLIP - NB_W - NB_Z - NB_HW - NB_W1T) * 256 + t;
        int o = tid2 >> 8, c = tid2 & 255;
        w2T[c * 256 + o] = w2[(size_t)o * 256 + c];
    }
}

// ---------------- MFMA conv GEMM (round-8 version, unchanged) ----------------
__global__ __launch_bounds__(256, 2)
void conv_mfma(const u16* __restrict__ CH, const u16* __restrict__ CL,
               const u16* __restrict__ WH, const u16* __restrict__ WL,
               const u16* __restrict__ ZS,
               float* __restrict__ XP0, float* __restrict__ XP1) {
    __shared__ __align__(16) u16 Ah[8192];
    __shared__ __align__(16) u16 Al[8192];
    __shared__ __align__(16) u16 Bh[8192];
    __shared__ __align__(16) u16 Bl[8192];

    const int t = threadIdx.x;
    const int gid = blockIdx.x;
    const int nb = gid >> 7;
    const int g  = gid & 127;
    const int mb = g >> 1;
    const int ks = g & 1;
    const int ksOff = ks * KHALF;
    float* __restrict__ XP = ks ? XP1 : XP0;

    const int wave = t >> 6, lane = t & 63;

    int qA[2], siA[2], sjA[2], bA[2];
    const u16* srcBh[2];
    const u16* srcBl[2];
#pragma unroll
    for (int j = 0; j < 2; ++j) {
        int r = wave * 32 + j * 16 + (lane >> 2);
        int s = lane & 3;
        int q = s ^ ((r >> 1) & 3);
        qA[j] = q;
        int m = mb * 128 + r;
        bA[j] = m >> 8;
        int ij = m & 255;
        siA[j] = ij >> 4; sjA[j] = ij & 15;
        int o = nb * 128 + r;
        srcBh[j] = WH + (size_t)o * K9 + q * 8;
        srcBl[j] = WL + (size_t)o * K9 + q * 8;
    }

    const int wm = wave >> 1, wn = wave & 1;
    const int l16 = lane & 15, quad = lane >> 4;
    int offA[4], offB[4];
#pragma unroll
    for (int q = 0; q < 4; ++q) {
        int ar = wm * 64 + q * 16 + l16;
        offA[q] = ar * 32 + ((quad ^ ((ar >> 1) & 3)) << 3);
        int br = wn * 64 + q * 16 + l16;
        offB[q] = br * 32 + ((quad ^ ((br >> 1) & 3)) << 3);
    }

    f32x4 acc[4][4];
#pragma unroll
    for (int r = 0; r < 4; ++r)
#pragma unroll
        for (int c = 0; c < 4; ++c) acc[r][c] = (f32x4){0.f, 0.f, 0.f, 0.f};

    auto issue = [&](int it, int buf) {
        const int kg = ksOff + it * 32;
        const int p = kg >> 10;
        const int cb = kg & 1023;
        const int di = p / 3, dj = p - di * 3;
        const int base = buf << 12;
#pragma unroll
        for (int j = 0; j < 2; ++j) {
            int ii = siA[j] + di - 1, jj = sjA[j] + dj - 1;
            bool ok = ((unsigned)ii < 16u) && ((unsigned)jj < 16u);
            size_t aoff = ok ? ((((size_t)bA[j] << 8) + (size_t)(ii * 16 + jj)) << 10) + cb + qA[j] * 8
                             : 0;
            const u16* gah = ok ? CH + aoff : ZS;
            const u16* gal = ok ? CL + aoff : ZS;
            int lb = base + wave * 1024 + j * 512;
            gl_lds16(gah,           &Ah[lb]);
            gl_lds16(gal,           &Al[lb]);
            gl_lds16(srcBh[j] + kg, &Bh[lb]);
            gl_lds16(srcBl[j] + kg, &Bl[lb]);
        }
    };

    issue(0, 0);
    for (int it = 0; it < 144; ++it) {
        const int cur = it & 1;
        __syncthreads();
        if (it + 1 < 144) issue(it + 1, cur ^ 1);

        const int fb = cur << 12;
        f16x8 fah[4], fal[4], fbh[4], fbl[4];
#pragma unroll
        for (int x = 0; x < 4; ++x) {
            fah[x] = *(const f16x8*)&Ah[fb + offA[x]];
            fal[x] = *(const f16x8*)&Al[fb + offA[x]];
            fbh[x] = *(const f16x8*)&Bh[fb + offB[x]];
            fbl[x] = *(const f16x8*)&Bl[fb + offB[x]];
        }
#pragma unroll
        for (int tm = 0; tm < 4; ++tm)
#pragma unroll
            for (int tn = 0; tn < 4; ++tn) {
                acc[tm][tn] = __builtin_amdgcn_mfma_f32_16x16x32_f16(fal[tm], fbh[tn], acc[tm][tn], 0, 0, 0);
                acc[tm][tn] = __builtin_amdgcn_mfma_f32_16x16x32_f16(fah[tm], fbl[tn], acc[tm][tn], 0, 0, 0);
                acc[tm][tn] = __builtin_amdgcn_mfma_f32_16x16x32_f16(fah[tm], fbh[tn], acc[tm][tn], 0, 0, 0);
            }
    }

#pragma unroll
    for (int tm = 0; tm < 4; ++tm) {
        int mbase = mb * 128 + wm * 64 + tm * 16 + quad * 4;
#pragma unroll
        for (int tn = 0; tn < 4; ++tn) {
            int o = nb * 128 + wn * 64 + tn * 16 + l16;
#pragma unroll
            for (int r = 0; r < 4; ++r)
                XP[(size_t)(mbase + r) * COUT + o] = acc[tm][tn][r];
        }
    }
}

// ---------------- heads (unchanged math) ----------------
__global__ __launch_bounds__(64)
void heads_kernel(const float* __restrict__ XP0, const float* __restrict__ XP1,
                  const float* __restrict__ conv_b, const float* __restrict__ HW,
                  const float* __restrict__ cls_b, const float* __restrict__ reg_b,
                  float* __restrict__ scores, float* __restrict__ regs) {
    __shared__ float xs[512];
    int mm = blockIdx.x;
    int t = threadIdx.x;
#pragma unroll
    for (int q = 0; q < 8; ++q) {
        int c = t + 64 * q;
        xs[c] = fmaxf(XP0[(size_t)mm * COUT + c] + XP1[(size_t)mm * COUT + c] + conv_b[c], 0.f);
    }
    __syncthreads();
    if (t < 45) {
        float acc = (t < 9) ? cls_b[t] : reg_b[t - 9];
        for (int c = 0; c < 512; ++c) acc = fmaf(xs[c], HW[c * 45 + t], acc);
        int b = mm >> 8, cell = mm & 255;
        if (t < 9) {
            scores[(size_t)b * 2304 + cell * 9 + t] = 1.f / (1.f + expf(-acc));
        } else {
            int ch = t - 9;
            regs[((size_t)b * 2304 + cell * 9 + (ch >> 2)) * 4 + (ch & 3)] = acc;
        }
    }
}

// ---------------- top-k + decode + NMS per image (unchanged) ----------------
__global__ __launch_bounds__(256)
void topk_nms(const float* __restrict__ scores, const float* __restrict__ regs,
              float* __restrict__ rois, float* __restrict__ valid) {
    __shared__ float sc[2304];
    __shared__ float wv[4];
    __shared__ int   wi[4];
    __shared__ int   sel[TOPK];
    __shared__ float bx[TOPK][4];
    __shared__ float iou[TOPK * TOPK];
    __shared__ float keepsh[TOPK];
    int b = blockIdx.x, t = threadIdx.x;
    for (int q = t; q < 2304; q += 256) sc[q] = scores[(size_t)b * 2304 + q];
    __syncthreads();

    for (int k = 0; k < TOPK; ++k) {
        float bv = -1e30f; int bi = 1 << 30;
#pragma unroll
        for (int q = 0; q < 9; ++q) {
            int idx = t * 9 + q;
            float v = sc[idx];
            if (v > bv || (v == bv && idx < bi)) { bv = v; bi = idx; }
        }
        for (int off = 32; off; off >>= 1) {
            float ov = __shfl_down(bv, off);
            int   oi = __shfl_down(bi, off);
            if (ov > bv || (ov == bv && oi < bi)) { bv = ov; bi = oi; }
        }
        int lane = t & 63, w = t >> 6;
        if (lane == 0) { wv[w] = bv; wi[w] = bi; }
        __syncthreads();
        if (t == 0) {
            float fv = wv[0]; int fi = wi[0];
            for (int q = 1; q < 4; ++q)
                if (wv[q] > fv || (wv[q] == fv && wi[q] < fi)) { fv = wv[q]; fi = wi[q]; }
            sel[k] = fi;
            sc[fi] = -1e38f;
        }
        __syncthreads();
    }

    if (t < TOPK) {
        int n = sel[t];
        int cell = n / 9, a = n % 9;
        int ci = cell >> 4, cj = cell & 15;
        int siid = a / 3, riid = a % 3;
        const double scl[3] = {8.0, 16.0, 32.0};
        const double rat[3] = {0.5, 1.0, 2.0};
        double s = scl[siid], r = rat[riid];
        double wD = s * sqrt(r), hD = s / sqrt(r);
        double xc = (cj + 0.5) * 16.0, yc = (ci + 0.5) * 16.0;
        float ax1 = (float)(xc - wD / 2), ay1 = (float)(yc - hD / 2);
        float ax2 = (float)(xc + wD / 2), ay2 = (float)(yc + hD / 2);
        float aw = ax2 - ax1, ah = ay2 - ay1;
        float ctrx = ax1 + 0.5f * aw, ctry = ay1 + 0.5f * ah;
        const float* rg = regs + ((size_t)b * 2304 + n) * 4;
        float cx = rg[0] * aw + ctrx;
        float cy = rg[1] * ah + ctry;
        float pw = expf(rg[2]) * aw;
        float ph = expf(rg[3]) * ah;
        float x1 = cx - 0.5f * pw, y1 = cy - 0.5f * ph;
        float x2 = cx + 0.5f * pw, y2 = cy + 0.5f * ph;
        x1 = fminf(fmaxf(x1, 0.f), 256.f);
        y1 = fminf(fmaxf(y1, 0.f), 256.f);
        x2 = fminf(fmaxf(x2, 0.f), 256.f);
        y2 = fminf(fmaxf(y2, 0.f), 256.f);
        if (x2 - x1 < 1.f) x2 = x1 + 1.f;
        if (y2 - y1 < 1.f) y2 = y1 + 1.f;
        bx[t][0] = x1; bx[t][1] = y1; bx[t][2] = x2; bx[t][3] = y2;
    }
    __syncthreads();
    if (t < TOPK * TOPK) {
        int ii = t / TOPK, jj = t % TOPK;
        float xi1 = bx[ii][0], yi1 = bx[ii][1], xi2 = bx[ii][2], yi2 = bx[ii][3];
        float xj1 = bx[jj][0], yj1 = bx[jj][1], xj2 = bx[jj][2], yj2 = bx[jj][3];
        float ai = (xi2 - xi1) * (yi2 - yi1), aj = (xj2 - xj1) * (yj2 - yj1);
        float iw = fmaxf(fminf(xi2, xj2) - fmaxf(xi1, xj1), 0.f);
        float ih = fmaxf(fminf(yi2, yj2) - fmaxf(yi1, yj1), 0.f);
        float inter = iw * ih;
        iou[t] = inter / (ai + aj - inter);
    }
    __syncthreads();
    if (t == 0) {
        bool keep[TOPK];
        for (int q = 0; q < TOPK; ++q) keep[q] = true;
        for (int iK = 0; iK < TOPK; ++iK) {
            if (!keep[iK]) continue;
            for (int jK = iK + 1; jK < TOPK; ++jK)
                if (keep[jK] && iou[iK * TOPK + jK] > 0.85f) keep[jK] = false;
        }
        for (int q = 0; q < TOPK; ++q) keepsh[q] = keep[q] ? 1.f : 0.f;
    }
    __syncthreads();
    if (t < TOPK) {
        int rr = b * TOPK + t;
        rois[rr * 4 + 0] = bx[t][0]; rois[rr * 4 + 1] = bx[t][1];
        rois[rr * 4 + 2] = bx[t][2]; rois[rr * 4 + 3] = bx[t][3];
        valid[rr] = keepsh[t];
    }
}

// ---------------- roi-align, image-sliced (round-9, kept) ----------------
__global__ __launch_bounds__(256)
void align_img(const float* __restrict__ clip, const float* __restrict__ rois,
               float* __restrict__ pooled) {
    __shared__ float slice[16384];   // 64 KB: [pos 0..255][ch 0..63]
    int bid = blockIdx.x;            // 0..511
    int b = bid >> 4, cg = bid & 15;
    int t = threadIdx.x;
    for (int idx = t; idx < 16384; idx += 256) {
        int p = idx >> 6, c = idx & 63;
        slice[idx] = clip[(size_t)(1 + p) * 32768 + (size_t)b * 1024 + cg * 64 + c];
    }
    __syncthreads();
    int wv = t >> 6;
    int ch = t & 63;
    for (int rp = 0; rp < 8; ++rp) {
        int rl = rp * 4 + wv;
        if (rl >= TOPK) continue;
        int r = b * TOPK + rl;
        float rx1 = rois[r * 4 + 0] * 0.0625f, ry1 = rois[r * 4 + 1] * 0.0625f;
        float rw = fmaxf(rois[r * 4 + 2] * 0.0625f - rx1, 1.f);
        float rh = fmaxf(rois[r * 4 + 3] * 0.0625f - ry1, 1.f);
        float sx = rw / (float)POOLN, sy = rh / (float)POOLN;
        float acc = 0.f;
        for (int py = 0; py < POOLN; ++py) {
            float Y = ry1 + ((float)py + 0.5f) * sy;
            for (int px = 0; px < POOLN; ++px) {
                float Xx = rx1 + ((float)px + 0.5f) * sx;
                bool ok = (Y > -1.f) && (Y < 16.f) && (Xx > -1.f) && (Xx < 16.f);
                if (!ok) continue;
                float Xc = fminf(fmaxf(Xx, 0.f), 15.f);
                float Yc = fminf(fmaxf(Y, 0.f), 15.f);
                int x0 = (int)floorf(Xc), y0 = (int)floorf(Yc);
                int x1i = min(x0 + 1, 15), y1i = min(y0 + 1, 15);
                float lx = Xc - (float)x0, ly = Yc - (float)y0;
                float hx = 1.f - lx, hy = 1.f - ly;
                float w00 = hy * hx, w01 = hy * lx, w10 = ly * hx, w11 = ly * lx;
                float f00 = slice[(y0 * 16 + x0) * 64 + ch];
                float f01 = slice[(y0 * 16 + x1i) * 64 + ch];
                float f10 = slice[(y1i * 16 + x0) * 64 + ch];
                float f11 = slice[(y1i * 16 + x1i) * 64 + ch];
                acc += w00 * f00 + w01 * f01 + w10 * f10 + w11 * f11;
            }
        }
        pooled[(size_t)r * 1024 + cg * 64 + ch] = acc / 49.f;
    }
}

// ---------------- roi labels (unchanged) ----------------
__global__ __launch_bounds__(256)
void labels_k(const float* __restrict__ gt, const float* __restrict__ rois,
              float* __restrict__ labels) {
    __shared__ float red[4];
    int r = blockIdx.x, t = threadIdx.x;
    int b = r / TOPK;
    int x1 = min(max((int)rois[r * 4 + 0], 0), 256);
    int y1 = min(max((int)rois[r * 4 + 1], 0), 256);
    int x2 = min(max((int)rois[r * 4 + 2], 0), 256);
    int y2 = min(max((int)rois[r * 4 + 3], 0), 256);
    int cnt = (x2 - x1) * (y2 - y1);
    float s = 0.f;
    if (cnt > 0) {
        const float* g = gt + (size_t)b * (IMG * IMG);
        for (int yy = y1; yy < y2; ++yy) {
            const float* row = g + yy * IMG;
            for (int xx = x1 + t; xx < x2; xx += 256) s += row[xx];
        }
    }
    for (int off = 32; off; off >>= 1) s += __shfl_down(s, off);
    if ((t & 63) == 0) red[t >> 6] = s;
    __syncthreads();
    if (t == 0) {
        float tot = red[0] + red[1] + red[2] + red[3];
        labels[r] = (cnt > 0 && 2.f * tot > (float)cnt) ? 1.f : 0.f;
    }
}

// ---------------- fused fc1(relu) -> fc2 -> normalize, 4 rois/block ----------------
__global__ __launch_bounds__(256)
void fc_norm(const float* __restrict__ pooled, const float* __restrict__ w1T,
             const float* __restrict__ b1, const float* __restrict__ w2T,
             const float* __restrict__ b2, float* __restrict__ nf) {
    __shared__ float rows[4][1024];
    __shared__ float hsh[4][256];
    __shared__ float red[4];
    int r0 = blockIdx.x * 4, t = threadIdx.x;
    for (int q = 0; q < 4; ++q)
        for (int c = t; c < 1024; c += 256)
            rows[q][c] = pooled[(size_t)(r0 + q) * 1024 + c];
    __syncthreads();
    {
        float bv = b1[t];
        float acc[4] = {bv, bv, bv, bv};
        for (int c = 0; c < 1024; ++c) {
            float wv = w1T[c * 256 + t];
#pragma unroll
            for (int q = 0; q < 4; ++q) acc[q] = fmaf(rows[q][c], wv, acc[q]);
        }
#pragma unroll
        for (int q = 0; q < 4; ++q) hsh[q][t] = fmaxf(acc[q], 0.f);
    }
    __syncthreads();
    float pr[4];
    {
        float bv = b2[t];
        float acc[4] = {bv, bv, bv, bv};
        for (int c = 0; c < 256; ++c) {
            float wv = w2T[c * 256 + t];
#pragma unroll
            for (int q = 0; q < 4; ++q) acc[q] = fmaf(hsh[q][c], wv, acc[q]);
        }
#pragma unroll
        for (int q = 0; q < 4; ++q) pr[q] = acc[q];
    }
    for (int q = 0; q < 4; ++q) {
        float v = pr[q];
        float ss = v * v;
        for (int off = 32; off; off >>= 1) ss += __shfl_down(ss, off);
        if ((t & 63) == 0) red[t >> 6] = ss;
        __syncthreads();
        float tot = red[0] + red[1] + red[2] + red[3];
        float denom = fmaxf(sqrtf(tot), 1e-12f);
        nf[(size_t)(r0 + q) * 256 + t] = v / denom;
        __syncthreads();
    }
}

// ---------------- supcon partials: block = (i, j-half), 1920 blocks ----------------
// Same per-(i,j) math as the round-8 single-row kernel; each block covers 480 j's.
// PS[i][half] = {sum_all, sum_pos, npos}. Always written (ws is poisoned).
__global__ __launch_bounds__(256)
void supcon_half(const float* __restrict__ nf, const float* __restrict__ labels,
                 const float* __restrict__ valid, float* __restrict__ PS) {
    __shared__ float my[256];
    __shared__ float labs[NROI], vals[NROI];
    __shared__ float wsa[4], wsp[4];
    __shared__ int wnp[4];
    int bid = blockIdx.x, t = threadIdx.x;
    int i = bid >> 1, half = bid & 1;
    my[t] = nf[(size_t)i * 256 + t];
    for (int q = t; q < NROI; q += 256) { labs[q] = labels[q]; vals[q] = valid[q]; }
    __syncthreads();
    float vi = vals[i], li = labs[i];
    float sum_all = 0.f, sum_pos = 0.f;
    int np = 0;
    int w = t >> 6, lane = t & 63;
    float4 my4 = ((const float4*)my)[lane];
    int j0 = half * 480, j1 = j0 + 480;
    if (vi > 0.5f) {
        for (int j = j0 + w; j < j1; j += 4) {
            float4 v4 = ((const float4*)(nf + (size_t)j * 256))[lane];
            float p = my4.x * v4.x;
            p = fmaf(my4.y, v4.y, p);
            p = fmaf(my4.z, v4.z, p);
            p = fmaf(my4.w, v4.w, p);
#pragma unroll
            for (int off = 32; off; off >>= 1) p += __shfl_xor(p, off);
            if (j != i && vals[j] > 0.5f) {
                float e = expf(p / 0.07f);
                sum_all += e;
                if (labs[j] == li) { sum_pos += e; np++; }
            }
        }
    }
    if (lane == 0) { wsa[w] = sum_all; wsp[w] = sum_pos; wnp[w] = np; }
    __syncthreads();
    if (t == 0) {
        float sa = wsa[0] + wsa[1] + wsa[2] + wsa[3];
        float sp = wsp[0] + wsp[1] + wsp[2] + wsp[3];
        int tnp = wnp[0] + wnp[1] + wnp[2] + wnp[3];
        PS[(size_t)i * 6 + half * 3 + 0] = sa;
        PS[(size_t)i * 6 + half * 3 + 1] = sp;
        PS[(size_t)i * 6 + half * 3 + 2] = (float)tnp;
    }
}

// ---------------- final: combine halves, per-row loss, mean ----------------
__global__ __launch_bounds__(256)
void final_reduce2(const float* __restrict__ PS, const float* __restrict__ valid,
                   float* __restrict__ out) {
    __shared__ float rl[4], ra[4];
    int t = threadIdx.x;
    float sl = 0.f, sc = 0.f;
    for (int i = t; i < NROI; i += 256) {
        float sa = PS[(size_t)i * 6 + 0] + PS[(size_t)i * 6 + 3];
        float sp = PS[(size_t)i * 6 + 1] + PS[(size_t)i * 6 + 4];
        float np = PS[(size_t)i * 6 + 2] + PS[(size_t)i * 6 + 5];
        bool active = (valid[i] > 0.5f) && (np > 0.5f);
        float ratio = sp / (sa + 1e-12f);
        float l = -logf(ratio + 1e-12f);
        sl += active ? l : 0.f;
        sc += active ? 1.f : 0.f;
    }
    for (int off = 32; off; off >>= 1) { sl += __shfl_down(sl, off); sc += __shfl_down(sc, off); }
    if ((t & 63) == 0) { rl[t >> 6] = sl; ra[t >> 6] = sc; }
    __syncthreads();
    if (t == 0) {
        float L = rl[0] + rl[1] + rl[2] + rl[3];
        float A = ra[0] + ra[1] + ra[2] + ra[3];
        out[0] = (A > 0.f) ? (L / fmaxf(A, 1.f)) : 0.f;
    }
}

// ---------------- launch ----------------
extern "C" void kernel_launch(void* const* d_in, const int* in_sizes, int n_in,
                              void* d_out, int out_size, void* d_ws, size_t ws_size,
                              hipStream_t stream) {
    const float* clip   = (const float*)d_in[0];
    const float* gt     = (const float*)d_in[1];
    const float* conv_w = (const float*)d_in[2];
    const float* conv_b = (const float*)d_in[3];
    const float* cls_w  = (const float*)d_in[4];
    const float* cls_b  = (const float*)d_in[5];
    const float* reg_w  = (const float*)d_in[6];
    const float* reg_b  = (const float*)d_in[7];
    const float* w1     = (const float*)d_in[8];
    const float* b1     = (const float*)d_in[9];
    const float* w2     = (const float*)d_in[10];
    const float* b2     = (const float*)d_in[11];

    if (ws_size < WS_FLOATS * sizeof(float)) return;  // visible failure if ws too small

    float* ws  = (float*)d_ws;
    float* XP0 = ws + O_XP0;
    float* XP1 = ws + O_XP1;
    u16*   CH  = (u16*)(ws + O_CH);
    u16*   CL  = (u16*)(ws + O_CL);
    u16*   WHp = (u16*)(ws + O_WH);
    u16*   WLp = (u16*)(ws + O_WL);
    u16*   ZS  = (u16*)(ws + O_Z);
    float* HW  = ws + O_HW;
    float* SC  = ws + O_SC;
    float* RG  = ws + O_RG;
    float* ROI = ws + O_ROI;
    float* VAL = ws + O_VAL;
    float* LAB = ws + O_LAB;
    float* W1T = ws + O_W1T;
    float* W2T = ws + O_W2T;
    float* PO  = ws + O_PO;
    float* NF  = ws + O_NF;
    float* PS  = ws + O_PS;

    convert_all<<<NB_CLIP + NB_W + NB_Z + NB_HW + NB_W1T + NB_W2T, 256, 0, stream>>>(
        clip, conv_w, cls_w, reg_w, w1, w2, CH, CL, WHp, WLp, ZS, HW, W1T, W2T);
    conv_mfma<<<512, 256, 0, stream>>>(CH, CL, WHp, WLp, ZS, XP0, XP1);
    heads_kernel<<<NPOS, 64, 0, stream>>>(XP0, XP1, conv_b, HW, cls_b, reg_b, SC, RG);
    topk_nms<<<BATCH, 256, 0, stream>>>(SC, RG, ROI, VAL);
    align_img<<<512, 256, 0, stream>>>(clip, ROI, PO);
    labels_k<<<NROI, 256, 0, stream>>>(gt, ROI, LAB);
    fc_norm<<<NROI / 4, 256, 0, stream>>>(PO, W1T, b1, W2T, b2, NF);
    supcon_half<<<2 * NROI, 256, 0, stream>>>(NF, LAB, VAL, PS);
    final_reduce2<<<1, 256, 0, stream>>>(PS, VAL, (float*)d_out);
}